// Round 4
// baseline (36.495 us; speedup 1.0000x reference)
//
#include <hip/hip_runtime.h>

// YOLO loss on (B,7,7,30) fp32 pred/target -> scalar.
// R3 post-mortem: atomics fixed (36us) but effective 5.3 TB/s with half the
// traffic L3-resident => latency-structure-bound, not BW-bound. R4: persistent
// 1-wave blocks, double-buffered LDS, counted s_waitcnt vmcnt(18) so the
// next tile's 18 global_load_lds stay in flight while computing the current
// tile. No __syncthreads anywhere (wave-self-contained staging).

#define NC 30
#define TPW 64                 // cells per wave-tile
#define TILE_DW (TPW * NC)     // 1920 dwords = 7680 B per tensor
#define MAXGRID 1280           // ~5 blocks/CU (LDS 30720B -> 5.2/CU)

__device__ __forceinline__ float sq(float x) { return x * x; }

__device__ __forceinline__ void g16(const float* g, float* l) {
    __builtin_amdgcn_global_load_lds(
        (const __attribute__((address_space(1))) unsigned int*)g,
        (__attribute__((address_space(3))) unsigned int*)l, 16, 0, 0);
}
__device__ __forceinline__ void g4(const float* g, float* l) {
    __builtin_amdgcn_global_load_lds(
        (const __attribute__((address_space(1))) unsigned int*)g,
        (__attribute__((address_space(3))) unsigned int*)l, 4, 0, 0);
}

// stage one wave-tile (7680B per tensor) into LDS: 7x 1KB width16 + 2x 256B
// width4 per tensor = 18 VMEM ops total. LDS dest wave-uniform, src per-lane.
__device__ __forceinline__ void stage_tile(const float* pb, const float* tb,
                                           float* sp, float* st, int lane) {
#pragma unroll
    for (int c = 0; c < 7; ++c) {
        g16(pb + c * 256 + lane * 4, sp + c * 256);
        g16(tb + c * 256 + lane * 4, st + c * 256);
    }
#pragma unroll
    for (int p = 0; p < 2; ++p) {
        g4(pb + 1792 + p * 64 + lane, sp + 1792 + p * 64);
        g4(tb + 1792 + p * 64 + lane, st + 1792 + p * 64);
    }
}

__device__ __forceinline__ void make_box(float cx, float cy, float w, float h,
                                         float jf, float kf, float b[4]) {
    float x = (cx + jf) * (1.0f / 7.0f);
    float y = (cy + kf) * (1.0f / 7.0f);
    b[0] = x - w * 0.5f;
    b[1] = y - h * 0.5f;
    b[2] = x + w * 0.5f;
    b[3] = y + h * 0.5f;
}

__device__ __forceinline__ float iou(const float a[4], const float b[4]) {
    float ix1 = fmaxf(a[0], b[0]);
    float iy1 = fmaxf(a[1], b[1]);
    float ix2 = fminf(a[2], b[2]);
    float iy2 = fminf(a[3], b[3]);
    float iw = fmaxf(ix2 - ix1, 0.0f);
    float ih = fmaxf(iy2 - iy1, 0.0f);
    float inter = iw * ih;
    float area_a = (a[2] - a[0]) * (a[3] - a[1]);
    float area_b = (b[2] - b[0]) * (b[3] - b[1]);
    return inter > 0.0f ? inter / (area_a + area_b - inter) : 0.0f;
}

__device__ __forceinline__ float cell_loss(const float* __restrict__ P,
                                           const float* __restrict__ T,
                                           float jf, float kf) {
    float b1[4], b2[4], tb[4];
    make_box(P[0], P[1], P[2], P[3], jf, kf, b1);
    make_box(P[5], P[6], P[7], P[8], jf, kf, b2);
    make_box(T[0], T[1], T[2], T[3], jf, kf, tb);

    float i1 = iou(b1, tb);
    float i2 = iou(b2, tb);

    bool obj = T[4] > 0.0f;
    bool pick1 = i1 >= i2;

    float cls = 0.0f;
#pragma unroll
    for (int e = 10; e < 30; ++e) {
        float d = P[e] - T[e];
        cls += d * d;
    }

    float coo1 = 5.0f * (sq(P[0] - T[0]) + sq(P[1] - T[1]) +
                         sq(sqrtf(P[2]) - sqrtf(T[2])) +
                         sq(sqrtf(P[3]) - sqrtf(T[3]))) +
                 sq(P[4] - i1);
    float non1 = 0.5f * sq(P[4] - i2);

    float coo2 = 5.0f * (sq(P[5] - T[5]) + sq(P[6] - T[6]) +
                         sq(sqrtf(P[7]) - sqrtf(T[7])) +
                         sq(sqrtf(P[8]) - sqrtf(T[8]))) +
                 sq(P[9] - i2);
    float non2 = 0.5f * sq(P[9] - i1);

    float noobj = 0.5f * (P[4] * P[4] + P[9] * P[9]);

    float resp = pick1 ? (coo1 + non1) : (coo2 + non2);
    return obj ? (resp + cls) : noobj;
}

__global__ __launch_bounds__(64) void yolo_partial_kernel(
    const float* __restrict__ pred, const float* __restrict__ targ,
    float* __restrict__ ws, int ncells, float scale) {
    __shared__ float sp[2][TILE_DW];
    __shared__ float st[2][TILE_DW];

    int lane = threadIdx.x;
    int bid = blockIdx.x;
    int nb = gridDim.x;
    int ntiles = ncells / TPW;

    float acc = 0.0f;
    int cur = 0;

    if (bid < ntiles)
        stage_tile(pred + (size_t)bid * TILE_DW, targ + (size_t)bid * TILE_DW,
                   sp[0], st[0], lane);

    for (int t = bid; t < ntiles; t += nb) {
        int tn = t + nb;
        if (tn < ntiles) {
            // prefetch next tile into the other buffer, then wait for the
            // CURRENT tile only (18 newest ops = the prefetch stay in flight;
            // vmcnt accounting is in issue order, m135).
            stage_tile(pred + (size_t)tn * TILE_DW,
                       targ + (size_t)tn * TILE_DW, sp[cur ^ 1], st[cur ^ 1],
                       lane);
            asm volatile("s_waitcnt vmcnt(18)" ::: "memory");
        } else {
            asm volatile("s_waitcnt vmcnt(0)" ::: "memory");
        }
        __builtin_amdgcn_sched_barrier(0);

        const float* P = sp[cur] + lane * NC;
        const float* T = st[cur] + lane * NC;
        int cell = t * TPW + lane;
        int q7 = cell / 7;
        int kc = cell - q7 * 7;
        int jc = q7 % 7;
        acc += cell_loss(P, T, (float)jc, (float)kc);
        __builtin_amdgcn_sched_barrier(0);  // keep ds_reads before next stage
        cur ^= 1;
    }

    // generic tail (ncells % 64 != 0) — scalar path, block 0 only
    int rem = ncells - ntiles * TPW;
    if (rem > 0 && bid == 0 && lane < rem) {
        float P[NC], T[NC];
        const float* pp = pred + (size_t)(ntiles * TPW + lane) * NC;
        const float* tt = targ + (size_t)(ntiles * TPW + lane) * NC;
#pragma unroll
        for (int e = 0; e < NC; ++e) {
            P[e] = pp[e];
            T[e] = tt[e];
        }
        int cell = ntiles * TPW + lane;
        int q7 = cell / 7;
        acc += cell_loss(P, T, (float)(q7 % 7), (float)(cell - q7 * 7));
    }

    // wave-64 reduction, one plain store per block
#pragma unroll
    for (int off = 32; off > 0; off >>= 1) acc += __shfl_down(acc, off);
    if (lane == 0) ws[bid] = acc * scale;
}

__global__ __launch_bounds__(1024) void reduce_kernel(
    const float* __restrict__ ws, float* __restrict__ out, int n) {
    float s = 0.0f;
    for (int i = threadIdx.x; i < n; i += 1024) s += ws[i];
#pragma unroll
    for (int off = 32; off > 0; off >>= 1) s += __shfl_down(s, off);

    __shared__ float acc[16];
    int wave = threadIdx.x >> 6;
    int lane = threadIdx.x & 63;
    if (lane == 0) acc[wave] = s;
    __syncthreads();

    if (threadIdx.x == 0) {
        float tot = 0.0f;
#pragma unroll
        for (int w = 0; w < 16; ++w) tot += acc[w];
        out[0] = tot;
    }
}

extern "C" void kernel_launch(void* const* d_in, const int* in_sizes, int n_in,
                              void* d_out, int out_size, void* d_ws, size_t ws_size,
                              hipStream_t stream) {
    const float* pred = (const float*)d_in[0];
    const float* targ = (const float*)d_in[1];
    float* out = (float*)d_out;

    int ncells = in_sizes[0] / NC;  // B*7*7
    int batch = ncells / 49;        // B
    float inv_b = 1.0f / (float)batch;

    int ntiles = ncells / TPW;
    int nb = ntiles < MAXGRID ? (ntiles > 0 ? ntiles : 1) : MAXGRID;
    size_t need = (size_t)nb * sizeof(float);
    if (ws_size < need) {
        int cap = (int)(ws_size / sizeof(float));
        nb = cap > 0 ? cap : 1;  // ws is >= 25KB in practice (R3 used 6272)
    }

    float* ws = (float*)d_ws;
    yolo_partial_kernel<<<nb, TPW, 0, stream>>>(pred, targ, ws, ncells, inv_b);
    reduce_kernel<<<1, 1024, 0, stream>>>(ws, out, nb);
}